// Round 14
// baseline (857.471 us; speedup 1.0000x reference)
//
#include <hip/hip_runtime.h>
#include <hip/hip_bf16.h>

#define NTOK 8192
#define DM 1024
#define DFF 4096
#define NE 8
#define TPAD 72  // max 256-row tiles: 16384/256 + 8 partials

typedef __attribute__((ext_vector_type(8))) short bf16x8;
typedef __attribute__((ext_vector_type(4))) float f32x4;

__device__ __forceinline__ ushort f2bf(float f) {
  __hip_bfloat16 h = __float2bfloat16(f);
  return *reinterpret_cast<ushort*>(&h);
}

// ---- pack W [e][K][N] fp32 -> chunks: series (e*(N/256)+nT), chunk kt32 (K/32),
// ---- layout [row=ncol 0..255][32 bf16 of K], ushort pos = j ^ ((row&6)<<2)
// ---- (byte4 ^= row-bit1, byte5 ^= row-bit2: 2-way-free LDS swizzle baked in).
template <int K, int N>
__global__ void pack_w(const float* __restrict__ in, ushort* __restrict__ outp) {
  __shared__ float t[64][257];
  const int e = blockIdx.z, nT = blockIdx.x, k64 = blockIdx.y;
  const float* src = in + (size_t)e * K * N + (size_t)k64 * 64 * N + (size_t)nT * 256;
  const int tid = threadIdx.x;
#pragma unroll
  for (int it = 0; it < 16; ++it) {
    int idx = it * 256 + tid;
    int kl = idx >> 6, n4 = idx & 63;
    float4 v = *reinterpret_cast<const float4*>(src + (size_t)kl * N + n4 * 4);
    t[kl][n4 * 4 + 0] = v.x; t[kl][n4 * 4 + 1] = v.y;
    t[kl][n4 * 4 + 2] = v.z; t[kl][n4 * 4 + 3] = v.w;
  }
  __syncthreads();
  const int r = tid;
  const int swap = (r & 6) << 2;  // ushort-granule XOR
#pragma unroll
  for (int s = 0; s < 2; ++s) {
    union { ushort us[32]; uint4 q[4]; } u;
#pragma unroll
    for (int j = 0; j < 32; ++j) u.us[j ^ swap] = f2bf(t[s * 32 + j][r]);
    ushort* dst = outp +
        ((size_t)(e * (N / 256) + nT) * (K / 32) + (k64 * 2 + s)) * 8192 + r * 32;
    uint4* d4 = reinterpret_cast<uint4*>(dst);
    d4[0] = u.q[0]; d4[1] = u.q[1]; d4[2] = u.q[2]; d4[3] = u.q[3];
  }
}

// ---------------- router (fused x->bf16 conversion) ----------------
__global__ void router_kernel(const float* __restrict__ x, const float* __restrict__ router,
                              int* __restrict__ cnt, int* __restrict__ list,
                              float* __restrict__ wa, ushort* __restrict__ xb) {
  __shared__ float rl[DM * NE];  // 32 KB
  int tid = threadIdx.x;
  for (int i = tid; i < DM * NE / 4; i += 256)
    reinterpret_cast<float4*>(rl)[i] = reinterpret_cast<const float4*>(router)[i];
  __syncthreads();
  int wave = tid >> 6, lane = tid & 63;
  int tok0 = blockIdx.x * 32 + wave * 8;
  for (int tI = 0; tI < 8; ++tI) {
    int tok = tok0 + tI;
    float acc[NE];
#pragma unroll
    for (int e2 = 0; e2 < NE; ++e2) acc[e2] = 0.f;
    const float4* xr = reinterpret_cast<const float4*>(x + (size_t)tok * DM);
    ushort xo[16];
#pragma unroll
    for (int c = 0; c < 4; ++c) {
      float4 v = xr[lane * 4 + c];
      int d = lane * 16 + c * 4;
      const float* vv = reinterpret_cast<const float*>(&v);
#pragma unroll
      for (int q = 0; q < 4; ++q) {
        float xv = vv[q];
        xo[c * 4 + q] = f2bf(xv);
#pragma unroll
        for (int e2 = 0; e2 < NE; ++e2) acc[e2] += xv * rl[(d + q) * NE + e2];
      }
    }
    *reinterpret_cast<uint4*>(xb + (size_t)tok * DM + lane * 16) =
        *reinterpret_cast<const uint4*>(&xo[0]);
    *reinterpret_cast<uint4*>(xb + (size_t)tok * DM + lane * 16 + 8) =
        *reinterpret_cast<const uint4*>(&xo[8]);
    for (int off = 32; off > 0; off >>= 1) {
#pragma unroll
      for (int e2 = 0; e2 < NE; ++e2) acc[e2] += __shfl_xor(acc[e2], off, 64);
    }
    if (lane == 0) {
      int i0 = 0; float v0 = acc[0];
#pragma unroll
      for (int e2 = 1; e2 < NE; ++e2) { if (acc[e2] > v0) { v0 = acc[e2]; i0 = e2; } }
      int i1 = -1; float v1 = -3.4e38f;
#pragma unroll
      for (int e2 = 0; e2 < NE; ++e2) { if (e2 != i0 && acc[e2] > v1) { v1 = acc[e2]; i1 = e2; } }
      float e1 = expf(v1 - v0);
      float w0 = 1.f / (1.f + e1);
      float w1 = e1 / (1.f + e1);
      int s0 = atomicAdd(&cnt[i0], 1);
      list[i0 * NTOK + s0] = tok * 2;
      wa[tok * 2] = w0;
      int s1 = atomicAdd(&cnt[i1], 1);
      list[i1 * NTOK + s1] = tok * 2 + 1;
      wa[tok * 2 + 1] = w1;
    }
  }
}

// ---------------- tile table: flat tile -> (expert, tTile), BM=256 ----------------
__global__ void build_tiles(const int* __restrict__ cnt, unsigned* __restrict__ table) {
  if (threadIdx.x == 0) {
    int t = 0;
    for (int e = 0; e < NE; ++e) {
      int nt = (cnt[e] + 255) >> 8;
      for (int i = 0; i < nt; ++i) table[t++] = ((unsigned)e << 16) | (unsigned)i;
    }
    for (; t < TPAD; ++t) table[t] = 0xFFFFFFFFu;
  }
}

// ---------------- helpers ----------------
__device__ __forceinline__ void gl_lds16(unsigned long long g, void* s) {
  __builtin_amdgcn_global_load_lds(
      (const __attribute__((address_space(1))) unsigned int*)g,
      (__attribute__((address_space(3))) unsigned int*)s, 16, 0, 0);
}

#define WAITV(N) asm volatile("s_waitcnt vmcnt(" #N ")" ::: "memory")

__device__ __forceinline__ void BARRIER() {
  asm volatile("" ::: "memory");
  __builtin_amdgcn_s_barrier();
  asm volatile("" ::: "memory");
}

// ------------- 256x256 phase-locked counted-vmcnt sparse expert GEMM -------------
// BK=32 K-tiles (A 16 KB + B 16 KB), ring-4 (128 KB LDS), 8 waves (2Mx4N),
// acc[8][4]. Per K-tile: WAITV(counted) -> BARRIER -> {ds_read frags; stage tile
// T+3 (4 gl_lds); 32 setprio'd MFMA}. ONE barrier per tile. Race-audit (R13 NaN
// fix): reads now AFTER the barrier; each wave's slot reads retire (compiler
// lgkmcnt before MFMA) before it reaches the next barrier, so staging slot
// (T+3)&3 after barrier T is WAR-safe; ring-4 absorbs the 1-barrier drift.
// vmcnt FIFO: at tile T's wait, tiles T+1,T+2 (8 instr) are newer -> WAITV(8)
// guarantees T landed; never drains until tail (8->4->0). LDS 64-B rows with
// (row&6)<<3 byte-XOR swizzle -> 2-way bank aliasing = free (m136).
template <int PASS>
__launch_bounds__(512, 2)
__global__ void moe_gemm(const ushort* __restrict__ Xb,
                         const ushort* __restrict__ Wp,
                         ushort* __restrict__ Hp,
                         const int* __restrict__ cnt,
                         const int* __restrict__ list,
                         const unsigned* __restrict__ table,
                         const float* __restrict__ wa,
                         float* __restrict__ out) {
  constexpr int NK = (PASS == 1) ? 32 : 64;  // 32-wide K-tiles (pass2: K=4096/2)

  const int bid = blockIdx.x;
  const int xcd = bid & 7;
  const int j = bid >> 3;
  int t, nTile, kc;
  if (PASS == 1) { t = j % TPAD; nTile = xcd * 2 + j / TPAD; kc = 0; }
  else           { t = j; nTile = xcd >> 1; kc = xcd & 1; }
  unsigned td = table[t];
  if (td == 0xFFFFFFFFu) return;  // uniform exit before any barrier
  const int e = td >> 16;
  const int tTile = td & 0xFFFF;
  const int n = cnt[e];

  __shared__ __attribute__((aligned(16))) char AsB[4 * 16384];
  __shared__ __attribute__((aligned(16))) char BsB[4 * 16384];
  __shared__ int aL[256];
  __shared__ unsigned long long pL[256];

  const int tid = threadIdx.x;
  if (tid < 256) {
    int slot = tTile * 256 + tid;
    int sl = (slot < n) ? slot : (n - 1);
    int a = list[e * NTOK + sl];
    aL[tid] = (slot < n) ? a : -1;
    if constexpr (PASS == 1)
      pL[tid] = (unsigned long long)(Xb + (size_t)(a >> 1) * DM);
  }
  __syncthreads();

  // ---- staging: per instr q in {0,1}: rows q*128 + (tid>>2), 16B at (tid&3)*16
  const int sr = tid >> 2;              // 0..127
  const int sq = (tid & 3) * 16;
  const unsigned swzc = (unsigned)(sq ^ ((sr & 6) << 3));  // gather-source swizzle
  unsigned long long pA0, pA1;
  if constexpr (PASS == 1) {
    pA0 = pL[sr] + swzc;                 // + T*64 at stage time
    pA1 = pL[128 + sr] + (unsigned)(sq ^ (((128 + sr) & 6) << 3));
  } else {
    const char* Asrc = (const char*)Hp + ((size_t)t * 128 + kc * 64) * 16384;
    pA0 = (unsigned long long)(Asrc + tid * 16);           // + T*16384
    pA1 = pA0 + 8192;
  }
  const size_t bChunk0 = (PASS == 1) ? ((size_t)(e * 16 + nTile) * 32)
                                     : ((size_t)(e * 4 + nTile) * 128 + kc * 64);
  const unsigned long long pB0 =
      (unsigned long long)((const char*)Wp + bChunk0 * 16384 + tid * 16);  // + T*16384
  const unsigned dstOff = (unsigned)(tid * 16);  // q adds 8192

  auto STG_A = [&](int s, int T) {
    if constexpr (PASS == 1) {
      gl_lds16(pA0 + (unsigned)T * 64, AsB + s * 16384 + dstOff);
      gl_lds16(pA1 + (unsigned)T * 64, AsB + s * 16384 + 8192 + dstOff);
    } else {
      gl_lds16(pA0 + (unsigned)T * 16384, AsB + s * 16384 + dstOff);
      gl_lds16(pA1 + (unsigned)T * 16384, AsB + s * 16384 + 8192 + dstOff);
    }
  };
  auto STG_B = [&](int s, int T) {
    gl_lds16(pB0 + (unsigned)T * 16384, BsB + s * 16384 + dstOff);
    gl_lds16(pB0 + (unsigned)T * 16384 + 8192, BsB + s * 16384 + 8192 + dstOff);
  };

  const int wv = tid >> 6, lane = tid & 63;
  const int wm = wv >> 2, wn = wv & 3;  // 2M x 4N; wave output 128x64
  const int l15 = lane & 15;
  const unsigned rswz = (unsigned)(((lane >> 4) * 16) ^ ((l15 & 6) << 3));
  const unsigned aRow0 = (unsigned)(wm * 128 + l15);  // + m*16 (doesn't touch bits 1-2)
  const unsigned bRow0 = (unsigned)(wn * 64 + l15);   // + nn*16

  f32x4 acc[8][4];
#pragma unroll
  for (int m = 0; m < 8; ++m)
#pragma unroll
    for (int nn = 0; nn < 4; ++nn) acc[m][nn] = (f32x4){0.f, 0.f, 0.f, 0.f};

  // prologue: tiles 0,1,2 into slots 0,1,2 (12 gl_lds); no drain.
  STG_A(0, 0); STG_B(0, 0);
  STG_A(1, 1); STG_B(1, 1);
  STG_A(2, 2); STG_B(2, 2);

  for (int T = 0; T < NK; ++T) {
    const int sT = T & 3;
    const int sN = (T + 3) & 3;
    const char* a_ = AsB + sT * 16384;
    const char* b_ = BsB + sT * 16384;
    // counted wait for tile T, then the ONLY barrier of this tile
    if (T < NK - 2) { WAITV(8); }
    else if (T == NK - 2) { WAITV(4); }
    else { WAITV(0); }
    BARRIER();  // all waves' tile-T loads landed; slot sN free for restage
    // ---- phase 1: B frags + A rows 0-63, stage A(T+3), MFMA m0-3 ----
    bf16x8 bq[4], af[4];
#pragma unroll
    for (int nn = 0; nn < 4; ++nn)
      bq[nn] = *reinterpret_cast<const bf16x8*>(b_ + (bRow0 + nn * 16) * 64 + rswz);
#pragma unroll
    for (int m = 0; m < 4; ++m)
      af[m] = *reinterpret_cast<const bf16x8*>(a_ + (aRow0 + m * 16) * 64 + rswz);
    if (T + 3 < NK) STG_A(sN, T + 3);
    __builtin_amdgcn_s_setprio(1);
#pragma unroll
    for (int m = 0; m < 4; ++m)
#pragma unroll
      for (int nn = 0; nn < 4; ++nn)
        acc[m][nn] = __builtin_amdgcn_mfma_f32_16x16x32_bf16(af[m], bq[nn], acc[m][nn], 0, 0, 0);
    __builtin_amdgcn_s_setprio(0);
    // ---- phase 2: A rows 64-127, stage B(T+3), MFMA m4-7 ----
#pragma unroll
    for (int m = 0; m < 4; ++m)
      af[m] = *reinterpret_cast<const bf16x8*>(a_ + (aRow0 + 64 + m * 16) * 64 + rswz);
    if (T + 3 < NK) STG_B(sN, T + 3);
    __builtin_amdgcn_s_setprio(1);
#pragma unroll
    for (int m = 0; m < 4; ++m)
#pragma unroll
      for (int nn = 0; nn < 4; ++nn)
        acc[4 + m][nn] = __builtin_amdgcn_mfma_f32_16x16x32_bf16(af[m], bq[nn], acc[4 + m][nn], 0, 0, 0);
    __builtin_amdgcn_s_setprio(0);
  }

  // epilogue — C/D layout: col = lane&15, row = (lane>>4)*4 + jr
#pragma unroll
  for (int m = 0; m < 8; ++m) {
#pragma unroll
    for (int jr = 0; jr < 4; ++jr) {
      int lr = wm * 128 + m * 16 + (lane >> 4) * 4 + jr;  // 0..255
      if constexpr (PASS == 1) {
        // packed-swizzled Hp: chunk = cg>>5, ushort pos = (cg&31) ^ ((lr&6)<<2)
        int sw = (lr & 6) << 2;
#pragma unroll
        for (int nn = 0; nn < 4; ++nn) {
          int cg = nTile * 256 + wn * 64 + nn * 16 + l15;
          float v = acc[m][nn][jr];
          size_t us = ((size_t)t * 128 + (cg >> 5)) * 8192 + (size_t)lr * 32 + ((cg & 31) ^ sw);
          Hp[us] = f2bf(v / (1.f + expf(-v)));  // swish
        }
      } else {
        int a = aL[lr];
        if (a < 0) continue;
        float w = wa[a];
        int tok = a >> 1;
        float* orow = out + (size_t)tok * DM + nTile * 256 + wn * 64 + l15;
#pragma unroll
        for (int nn = 0; nn < 4; ++nn)
          atomicAdd(&orow[nn * 16], w * acc[m][nn][jr]);  // 2 experts x 2 kc, commutative
      }
    }
  }
}

extern "C" void kernel_launch(void* const* d_in, const int* in_sizes, int n_in,
                              void* d_out, int out_size, void* d_ws, size_t ws_size,
                              hipStream_t stream) {
  const float* x = (const float*)d_in[0];
  const float* router = (const float*)d_in[1];
  const float* W1 = (const float*)d_in[2];
  const float* W2 = (const float*)d_in[3];
  float* out = (float*)d_out;
  char* ws = (char*)d_ws;

  // [0,80 MB): Xb (16) + Wp1 (64) during pass1; Wp2 (64) aliases [0,64) after pass1.
  ushort* Xb  = (ushort*)(ws + 0);
  ushort* Wp1 = (ushort*)(ws + (size_t)16 * 1024 * 1024);
  ushort* Wp2 = (ushort*)(ws + 0);
  size_t off = (size_t)80 * 1024 * 1024;
  ushort* Hp = (ushort*)(ws + off); off += (size_t)TPAD * 128 * 16384;  // 151 MB
  int* cnt  = (int*)(ws + off); off += 256;
  int* list = (int*)(ws + off); off += (size_t)NE * NTOK * 4;
  float* wa = (float*)(ws + off); off += (size_t)NTOK * 2 * 4;
  unsigned* table = (unsigned*)(ws + off); off += TPAD * 4;

  hipMemsetAsync(out, 0, (size_t)NTOK * DM * sizeof(float), stream);
  hipMemsetAsync(cnt, 0, NE * sizeof(int), stream);

  pack_w<DM, DFF><<<dim3(DFF / 256, DM / 64, NE), 256, 0, stream>>>(W1, Wp1);
  router_kernel<<<NTOK / 32, 256, 0, stream>>>(x, router, cnt, list, wa, Xb);
  build_tiles<<<1, 64, 0, stream>>>(cnt, table);

  // pass1: 16 nTiles -> 2 chunks/XCD, tile-fastest; grid 8*2*72 = 1152
  moe_gemm<1><<<8 * 2 * TPAD, 512, 0, stream>>>(Xb, Wp1, Hp, cnt, list, table, wa, out);

  pack_w<DFF, DM><<<dim3(DM / 256, DFF / 64, NE), 256, 0, stream>>>(W2, Wp2);

  // pass2: 4 nTiles x 2 kc on the 8 XCDs; grid 8*72 = 576
  moe_gemm<2><<<8 * TPAD, 512, 0, stream>>>(Xb, Wp2, Hp, cnt, list, table, wa, out);
}

// Round 16
// 711.377 us; speedup vs baseline: 1.2054x; 1.2054x over previous
//
#include <hip/hip_runtime.h>
#include <hip/hip_bf16.h>

#define NTOK 8192
#define DM 1024
#define DFF 4096
#define NE 8
#define MAXT 136  // max 128-row tiles: 16384/128 + 8 partials

typedef __attribute__((ext_vector_type(8))) short bf16x8;
typedef __attribute__((ext_vector_type(4))) float f32x4;

__device__ __forceinline__ ushort f2bf(float f) {
  __hip_bfloat16 h = __float2bfloat16(f);
  return *reinterpret_cast<ushort*>(&h);
}

// ---- pack W [e][K][N] fp32 -> Wp chunks keyed (e*(N/128)+nT)*(K/64)+kt of
// ---- [row128][64 ushort], swizzle baked: ushort pos u holds col u^((row&7)<<3).
// ---- (R9-proven body: XOR applied on READ side, contiguous 32-ushort store.)
template <int K, int N>
__global__ void pack_w(const float* __restrict__ in, ushort* __restrict__ outp) {
  __shared__ float t[64][129];
  const int e = blockIdx.z, nT = blockIdx.x, kt = blockIdx.y;
  const float* src = in + (size_t)e * K * N + (size_t)kt * 64 * N + (size_t)nT * 128;
  const int tid = threadIdx.x;
#pragma unroll
  for (int it = 0; it < 8; ++it) {
    int idx = it * 256 + tid;
    int kl = idx >> 5, n4 = idx & 31;
    f32x4 v = __builtin_nontemporal_load(
        reinterpret_cast<const f32x4*>(src + (size_t)kl * N + n4 * 4));
    t[kl][n4 * 4 + 0] = v.x; t[kl][n4 * 4 + 1] = v.y;
    t[kl][n4 * 4 + 2] = v.z; t[kl][n4 * 4 + 3] = v.w;
  }
  __syncthreads();
  const int row = tid >> 1, half = tid & 1;
  const int s = (row & 7) << 3;
  union { ushort us[32]; uint4 q[4]; } u;
#pragma unroll
  for (int k2 = 0; k2 < 32; ++k2) u.us[k2] = f2bf(t[(half * 32 + k2) ^ s][row]);
  ushort* dst = outp + ((size_t)(e * (N / 128) + nT) * (K / 64) + kt) * 8192 + row * 64 + half * 32;
  uint4* d4 = reinterpret_cast<uint4*>(dst);
  d4[0] = u.q[0]; d4[1] = u.q[1]; d4[2] = u.q[2]; d4[3] = u.q[3];
}

// ---------------- router (fused x->bf16 conversion) ----------------
__global__ void router_kernel(const float* __restrict__ x, const float* __restrict__ router,
                              int* __restrict__ cnt, int* __restrict__ list,
                              float* __restrict__ wa, ushort* __restrict__ xb) {
  __shared__ float rl[DM * NE];  // 32 KB
  int tid = threadIdx.x;
  for (int i = tid; i < DM * NE / 4; i += 256)
    reinterpret_cast<float4*>(rl)[i] = reinterpret_cast<const float4*>(router)[i];
  __syncthreads();
  int wave = tid >> 6, lane = tid & 63;
  int tok0 = blockIdx.x * 32 + wave * 8;
  for (int tI = 0; tI < 8; ++tI) {
    int tok = tok0 + tI;
    float acc[NE];
#pragma unroll
    for (int e2 = 0; e2 < NE; ++e2) acc[e2] = 0.f;
    const float4* xr = reinterpret_cast<const float4*>(x + (size_t)tok * DM);
    ushort xo[16];
#pragma unroll
    for (int c = 0; c < 4; ++c) {
      float4 v = xr[lane * 4 + c];
      int d = lane * 16 + c * 4;
      const float* vv = reinterpret_cast<const float*>(&v);
#pragma unroll
      for (int q = 0; q < 4; ++q) {
        float xv = vv[q];
        xo[c * 4 + q] = f2bf(xv);
#pragma unroll
        for (int e2 = 0; e2 < NE; ++e2) acc[e2] += xv * rl[(d + q) * NE + e2];
      }
    }
    *reinterpret_cast<uint4*>(xb + (size_t)tok * DM + lane * 16) =
        *reinterpret_cast<const uint4*>(&xo[0]);
    *reinterpret_cast<uint4*>(xb + (size_t)tok * DM + lane * 16 + 8) =
        *reinterpret_cast<const uint4*>(&xo[8]);
    for (int off = 32; off > 0; off >>= 1) {
#pragma unroll
      for (int e2 = 0; e2 < NE; ++e2) acc[e2] += __shfl_xor(acc[e2], off, 64);
    }
    if (lane == 0) {
      int i0 = 0; float v0 = acc[0];
#pragma unroll
      for (int e2 = 1; e2 < NE; ++e2) { if (acc[e2] > v0) { v0 = acc[e2]; i0 = e2; } }
      int i1 = -1; float v1 = -3.4e38f;
#pragma unroll
      for (int e2 = 0; e2 < NE; ++e2) { if (e2 != i0 && acc[e2] > v1) { v1 = acc[e2]; i1 = e2; } }
      float e1 = expf(v1 - v0);
      float w0 = 1.f / (1.f + e1);
      float w1 = e1 / (1.f + e1);
      int s0 = atomicAdd(&cnt[i0], 1);
      list[i0 * NTOK + s0] = tok * 2;
      wa[tok * 2] = w0;
      int s1 = atomicAdd(&cnt[i1], 1);
      list[i1 * NTOK + s1] = tok * 2 + 1;
      wa[tok * 2 + 1] = w1;
    }
  }
}

// ---------------- helpers ----------------
__device__ __forceinline__ void gl_lds16(unsigned long long g, void* s) {
  __builtin_amdgcn_global_load_lds(
      (const __attribute__((address_space(1))) unsigned int*)g,
      (__attribute__((address_space(3))) unsigned int*)s, 16, 0, 0);
}

#define WAITV0() asm volatile("s_waitcnt vmcnt(0)" ::: "memory")

__device__ __forceinline__ void BARRIER() {
  asm volatile("" ::: "memory");
  __builtin_amdgcn_s_barrier();
  asm volatile("" ::: "memory");
}

// ------------- 128x256 / 8-wave / single-buffer sparse expert GEMM -------------
// Staged-bytes law (R8/R9/R12/R14: 12-16 B/cy/CU invariant): BN=256 cuts staged
// bytes/FLOP 1/64 -> 1/85 vs 128^2. LDS 48KB+meta -> 2 blocks/CU, 16 waves/CU
// (the VGPR-capped max). R9's proven body: stage -> vmcnt(0) -> barrier ->
// compute -> barrier. Packed linear B streams (swizzle baked), R8 gather for
// pass1 A, packed Hp for pass2 A. Tile table folded into per-block scalar
// prefix over cnt (build_tiles launch eliminated).
template <int PASS>
__launch_bounds__(512, 2)
__global__ void moe_gemm(const ushort* __restrict__ Xb,
                         const ushort* __restrict__ Wp,
                         ushort* __restrict__ Hp,
                         const int* __restrict__ cnt,
                         const int* __restrict__ list,
                         const float* __restrict__ wa,
                         float* __restrict__ out) {
  constexpr int NK = (PASS == 1) ? 16 : 32;  // pass2: K=4096 split 2

  const int bid = blockIdx.x;
  const int xcd = bid & 7;
  const int j = bid >> 3;
  int t, nTile, kc;
  if (PASS == 1) { t = j % MAXT; nTile = xcd * 2 + j / MAXT; kc = 0; }
  else           { t = j; nTile = xcd >> 1; kc = xcd & 1; }
  // resolve (e, tTile) from cnt prefix (replaces build_tiles kernel)
  int e = -1, tTile = 0, accT = 0;
#pragma unroll
  for (int ee = 0; ee < NE; ++ee) {
    int nt = (cnt[ee] + 127) >> 7;
    if (e < 0 && t < accT + nt) { e = ee; tTile = t - accT; }
    accT += nt;
  }
  if (e < 0) return;  // uniform exit before any barrier
  const int n = cnt[e];

  __shared__ __attribute__((aligned(16))) char As[16384];   // 128 x 128B
  __shared__ __attribute__((aligned(16))) char Bs[32768];   // 256 x 128B
  __shared__ int aL[128];
  __shared__ unsigned long long pL[128];

  const int tid = threadIdx.x;
  if (tid < 128) {
    int slot = tTile * 128 + tid;
    int sl = (slot < n) ? slot : (n - 1);
    int a = list[e * NTOK + sl];
    aL[tid] = (slot < n) ? a : -1;
    if (PASS == 1) pL[tid] = (unsigned long long)(Xb + (size_t)(a >> 1) * DM);
  }
  __syncthreads();

  // ---- A staging: 2 instr x 8KB; row = q*64 + (tid>>3), col (tid&7)*16 ----
  const int srow = tid >> 3;
  const int sc = (tid & 7) * 16;
  unsigned long long sA[2];
  if constexpr (PASS == 1) {
#pragma unroll
    for (int q = 0; q < 2; ++q) {
      int row = q * 64 + srow;
      sA[q] = pL[row] + (unsigned)(sc ^ ((row & 7) << 4));  // source-swizzled gather
    }
  } else {
    const char* Asrc = (const char*)Hp + ((size_t)t * 64 + kc * 32) * 16384;
#pragma unroll
    for (int q = 0; q < 2; ++q) sA[q] = (unsigned long long)(Asrc + q * 8192 + tid * 16);
  }
  // ---- B staging: 4 instr x 8KB from 2 packed 128-col series ----
  unsigned long long sB[4];
#pragma unroll
  for (int jj = 0; jj < 4; ++jj) {
    size_t series = (PASS == 1) ? ((size_t)e * 32 + nTile * 2 + (jj >> 1))
                                : ((size_t)e * 8 + nTile * 2 + (jj >> 1));
    size_t chunk0 = (PASS == 1) ? (series * 16) : (series * 64 + kc * 32);
    sB[jj] = (unsigned long long)((const char*)Wp + chunk0 * 16384 + (jj & 1) * 8192 + tid * 16);
  }

  const int wv = tid >> 6, lane = tid & 63;
  const int wm = wv >> 2, wn = wv & 3;  // 2M x 4N; wave output 64x64
  const int l15 = lane & 15;

  f32x4 acc[4][4];
#pragma unroll
  for (int m = 0; m < 4; ++m)
#pragma unroll
    for (int nn = 0; nn < 4; ++nn) acc[m][nn] = (f32x4){0.f, 0.f, 0.f, 0.f};

  for (int kt = 0; kt < NK; ++kt) {
    // STAGE tile kt into the single buffer
    if constexpr (PASS == 1) {
#pragma unroll
      for (int q = 0; q < 2; ++q)
        gl_lds16(sA[q] + (unsigned)kt * 128, As + q * 8192 + tid * 16);
    } else {
#pragma unroll
      for (int q = 0; q < 2; ++q)
        gl_lds16(sA[q] + (unsigned)kt * 16384, As + q * 8192 + tid * 16);
    }
#pragma unroll
    for (int jj = 0; jj < 4; ++jj)
      gl_lds16(sB[jj] + (unsigned)kt * 16384, Bs + jj * 8192 + tid * 16);
    WAITV0();
    BARRIER();
    // COMPUTE
#pragma unroll
    for (int kk = 0; kk < 2; ++kk) {
      const int kb = kk * 64 + (lane >> 4) * 16;
      bf16x8 af[4], bq[4];
#pragma unroll
      for (int m = 0; m < 4; ++m) {
        int row = wm * 64 + m * 16 + l15;
        af[m] = *reinterpret_cast<const bf16x8*>(As + row * 128 + (kb ^ ((row & 7) << 4)));
      }
#pragma unroll
      for (int nn = 0; nn < 4; ++nn) {
        int row = wn * 64 + nn * 16 + l15;
        bq[nn] = *reinterpret_cast<const bf16x8*>(Bs + row * 128 + (kb ^ ((row & 7) << 4)));
      }
      __builtin_amdgcn_s_setprio(1);
#pragma unroll
      for (int m = 0; m < 4; ++m)
#pragma unroll
        for (int nn = 0; nn < 4; ++nn)
          acc[m][nn] = __builtin_amdgcn_mfma_f32_16x16x32_bf16(af[m], bq[nn], acc[m][nn], 0, 0, 0);
      __builtin_amdgcn_s_setprio(0);
    }
    BARRIER();  // WAR before next stage overwrites
  }

  // epilogue — C/D layout: col = lane&15, row = (lane>>4)*4 + jr
#pragma unroll
  for (int m = 0; m < 4; ++m) {
#pragma unroll
    for (int jr = 0; jr < 4; ++jr) {
      int lr = wm * 64 + m * 16 + (lane >> 4) * 4 + jr;  // 0..127
      if constexpr (PASS == 1) {
        // packed-swizzled Hp chunks (t, cg64): [row128][64us], pos (cg&63)^((lr&7)<<3)
#pragma unroll
        for (int nn = 0; nn < 4; ++nn) {
          int cg = nTile * 256 + wn * 64 + nn * 16 + l15;
          float v = acc[m][nn][jr];
          size_t us = ((size_t)t * 64 + (cg >> 6)) * 8192 + (size_t)lr * 64 +
                      ((cg & 63) ^ ((lr & 7) << 3));
          Hp[us] = f2bf(v / (1.f + expf(-v)));  // swish
        }
      } else {
        int a = aL[lr];
        if (a < 0) continue;
        float w = wa[a];
        int tok = a >> 1;
        float* orow = out + (size_t)tok * DM + nTile * 256 + wn * 64 + l15;
#pragma unroll
        for (int nn = 0; nn < 4; ++nn)
          atomicAdd(&orow[nn * 16], w * acc[m][nn][jr]);  // 2 experts x 2 kc, commutative
      }
    }
  }
}

extern "C" void kernel_launch(void* const* d_in, const int* in_sizes, int n_in,
                              void* d_out, int out_size, void* d_ws, size_t ws_size,
                              hipStream_t stream) {
  const float* x = (const float*)d_in[0];
  const float* router = (const float*)d_in[1];
  const float* W1 = (const float*)d_in[2];
  const float* W2 = (const float*)d_in[3];
  float* out = (float*)d_out;
  char* ws = (char*)d_ws;

  // [0,80 MB): Xb (16) + Wp1 (64) during pass1; Wp2 (64) aliases [0,64) after pass1.
  ushort* Xb  = (ushort*)(ws + 0);
  ushort* Wp1 = (ushort*)(ws + (size_t)16 * 1024 * 1024);
  ushort* Wp2 = (ushort*)(ws + 0);
  size_t off = (size_t)80 * 1024 * 1024;
  ushort* Hp = (ushort*)(ws + off); off += (size_t)MAXT * 64 * 16384;  // 142.6 MB
  int* cnt  = (int*)(ws + off); off += 256;
  int* list = (int*)(ws + off); off += (size_t)NE * NTOK * 4;
  float* wa = (float*)(ws + off); off += (size_t)NTOK * 2 * 4;

  hipMemsetAsync(out, 0, (size_t)NTOK * DM * sizeof(float), stream);
  hipMemsetAsync(cnt, 0, NE * sizeof(int), stream);

  pack_w<DM, DFF><<<dim3(DFF / 128, DM / 64, NE), 256, 0, stream>>>(W1, Wp1);
  router_kernel<<<NTOK / 32, 256, 0, stream>>>(x, router, cnt, list, wa, Xb);

  // pass1: 16 nTiles(256) -> 2 chunks/XCD, tile-fastest; grid 8*2*136 = 2176
  moe_gemm<1><<<8 * 2 * MAXT, 512, 0, stream>>>(Xb, Wp1, Hp, cnt, list, wa, out);

  pack_w<DFF, DM><<<dim3(DM / 128, DFF / 64, NE), 256, 0, stream>>>(W2, Wp2);

  // pass2: 4 nTiles(256) x 2 kc on the 8 XCDs; grid 8*136 = 1088
  moe_gemm<2><<<8 * MAXT, 512, 0, stream>>>(Xb, Wp2, Hp, cnt, list, wa, out);
}

// Round 17
// 652.765 us; speedup vs baseline: 1.3136x; 1.0898x over previous
//
#include <hip/hip_runtime.h>
#include <hip/hip_bf16.h>

#define NTOK 8192
#define DM 1024
#define DFF 4096
#define NE 8
#define MAXT 136  // max 128-row tiles: 16384/128 + 8 partials

typedef __attribute__((ext_vector_type(8))) short bf16x8;
typedef __attribute__((ext_vector_type(4))) float f32x4;

__device__ __forceinline__ ushort f2bf(float f) {
  __hip_bfloat16 h = __float2bfloat16(f);
  return *reinterpret_cast<ushort*>(&h);
}

// ---------------- shared-memory union (GEMM / pack / router paths) ----------------
struct GemmSM {
  alignas(16) char As[16384];
  alignas(16) char Bs[16384];
  int aL[128];
  unsigned long long pL[128];
};
union SMem {
  GemmSM g;
  float t[64][129];    // pack transpose buffer (33 KB)
  float rl[DM * NE];   // router weights (32 KB)
};

// ---- pack one 64K x 128N block of W [e][K][N] fp32 -> packed-swizzled bf16 chunk
// ---- chunk key (e*(N/128)+nT)*(K/64)+kt, layout [row128][64us], pos u = col^((row&7)<<3)
__device__ __forceinline__ void pack_block(const float* __restrict__ in,
                                           ushort* __restrict__ outp, int bid,
                                           int K, int N, float (&t)[64][129]) {
  const int nTn = N >> 7, ktn = K >> 6;
  const int perE = nTn * ktn;  // 512 for both W1 and W2
  const int e = bid / perE, rem = bid % perE;
  const int nT = rem % nTn, kt = rem / nTn;
  const float* src = in + (size_t)e * K * N + (size_t)kt * 64 * N + (size_t)nT * 128;
  const int tid = threadIdx.x;
#pragma unroll
  for (int it = 0; it < 8; ++it) {
    int idx = it * 256 + tid;
    int kl = idx >> 5, n4 = idx & 31;
    f32x4 v = __builtin_nontemporal_load(
        reinterpret_cast<const f32x4*>(src + (size_t)kl * N + n4 * 4));
    t[kl][n4 * 4 + 0] = v.x; t[kl][n4 * 4 + 1] = v.y;
    t[kl][n4 * 4 + 2] = v.z; t[kl][n4 * 4 + 3] = v.w;
  }
  __syncthreads();
  const int row = tid >> 1, half = tid & 1;
  const int s = (row & 7) << 3;
  union { ushort us[32]; uint4 q[4]; } u;
#pragma unroll
  for (int k2 = 0; k2 < 32; ++k2) u.us[k2] = f2bf(t[(half * 32 + k2) ^ s][row]);
  ushort* dst = outp + ((size_t)(e * nTn + nT) * ktn + kt) * 8192 + row * 64 + half * 32;
  uint4* d4 = reinterpret_cast<uint4*>(dst);
  d4[0] = u.q[0]; d4[1] = u.q[1]; d4[2] = u.q[2]; d4[3] = u.q[3];
}

// ---------------- router block (fused x->bf16 conversion) ----------------
__device__ __forceinline__ void router_block(const float* __restrict__ x,
                                             const float* __restrict__ rtr,
                                             int* __restrict__ cnt, int* __restrict__ list,
                                             float* __restrict__ wa, ushort* __restrict__ xb,
                                             int rbid, float* rl) {
  int tid = threadIdx.x;
  for (int i = tid; i < DM * NE / 4; i += 256)
    reinterpret_cast<float4*>(rl)[i] = reinterpret_cast<const float4*>(rtr)[i];
  __syncthreads();
  int wave = tid >> 6, lane = tid & 63;
  int tok0 = rbid * 32 + wave * 8;
  for (int tI = 0; tI < 8; ++tI) {
    int tok = tok0 + tI;
    float acc[NE];
#pragma unroll
    for (int e2 = 0; e2 < NE; ++e2) acc[e2] = 0.f;
    const float4* xr = reinterpret_cast<const float4*>(x + (size_t)tok * DM);
    ushort xo[16];
#pragma unroll
    for (int c = 0; c < 4; ++c) {
      float4 v = xr[lane * 4 + c];
      int d = lane * 16 + c * 4;
      const float* vv = reinterpret_cast<const float*>(&v);
#pragma unroll
      for (int q = 0; q < 4; ++q) {
        float xv = vv[q];
        xo[c * 4 + q] = f2bf(xv);
#pragma unroll
        for (int e2 = 0; e2 < NE; ++e2) acc[e2] += xv * rl[(d + q) * NE + e2];
      }
    }
    *reinterpret_cast<uint4*>(xb + (size_t)tok * DM + lane * 16) =
        *reinterpret_cast<const uint4*>(&xo[0]);
    *reinterpret_cast<uint4*>(xb + (size_t)tok * DM + lane * 16 + 8) =
        *reinterpret_cast<const uint4*>(&xo[8]);
    for (int off = 32; off > 0; off >>= 1) {
#pragma unroll
      for (int e2 = 0; e2 < NE; ++e2) acc[e2] += __shfl_xor(acc[e2], off, 64);
    }
    if (lane == 0) {
      int i0 = 0; float v0 = acc[0];
#pragma unroll
      for (int e2 = 1; e2 < NE; ++e2) { if (acc[e2] > v0) { v0 = acc[e2]; i0 = e2; } }
      int i1 = -1; float v1 = -3.4e38f;
#pragma unroll
      for (int e2 = 0; e2 < NE; ++e2) { if (e2 != i0 && acc[e2] > v1) { v1 = acc[e2]; i1 = e2; } }
      float e1 = expf(v1 - v0);
      float w0 = 1.f / (1.f + e1);
      float w1 = e1 / (1.f + e1);
      int s0 = atomicAdd(&cnt[i0], 1);
      list[i0 * NTOK + s0] = tok * 2;
      wa[tok * 2] = w0;
      int s1 = atomicAdd(&cnt[i1], 1);
      list[i1 * NTOK + s1] = tok * 2 + 1;
      wa[tok * 2 + 1] = w1;
    }
  }
}

// ---------------- helpers ----------------
__device__ __forceinline__ void gl_lds16(unsigned long long g, void* s) {
  __builtin_amdgcn_global_load_lds(
      (const __attribute__((address_space(1))) unsigned int*)g,
      (__attribute__((address_space(3))) unsigned int*)s, 16, 0, 0);
}

#define WAITV0() asm volatile("s_waitcnt vmcnt(0)" ::: "memory")

__device__ __forceinline__ void BARRIER() {
  asm volatile("" ::: "memory");
  __builtin_amdgcn_s_barrier();
  asm volatile("" ::: "memory");
}

// ------------- R9-optimal sparse expert GEMM body (128^2, 4 waves, 4 blk/CU) -------------
// Single-buffer 33.5 KB LDS; body stage -> vmcnt(0) -> barrier -> compute -> barrier.
// 4 blk/CU gives the measured-max 10 TB/s staging service rate (R8/R9 vs R12/R14/R16).
// Packed linear B (swizzle baked), source-swizzled A-gather (pass1), packed Hp (pass2).
template <int PASS>
__device__ __forceinline__ void gemm_body(GemmSM& smg, int bid,
                                          const ushort* __restrict__ Xb,
                                          const ushort* __restrict__ Wp,
                                          ushort* __restrict__ Hp,
                                          const int* __restrict__ cnt,
                                          const int* __restrict__ list,
                                          const float* __restrict__ wa,
                                          float* __restrict__ out) {
  constexpr int NK = (PASS == 1) ? 16 : 32;  // pass2: K=4096 split 2

  const int xcd = bid & 7;
  const int j = bid >> 3;
  int t, nTile, kc;
  if (PASS == 1) { t = j >> 2; nTile = xcd * 4 + (j & 3); kc = 0; }  // c-fastest
  else           { t = j >> 1; nTile = xcd; kc = j & 1; }
  // resolve (e, tTile) from cnt prefix
  int e = -1, tTile = 0, accT = 0;
#pragma unroll
  for (int ee = 0; ee < NE; ++ee) {
    int nt = (cnt[ee] + 127) >> 7;
    if (e < 0 && t < accT + nt) { e = ee; tTile = t - accT; }
    accT += nt;
  }
  if (e < 0) return;  // uniform exit before any barrier
  const int n = cnt[e];

  const int tid = threadIdx.x;
  if (tid < 128) {
    int slot = tTile * 128 + tid;
    int sl = (slot < n) ? slot : (n - 1);
    int a = list[e * NTOK + sl];
    smg.aL[tid] = (slot < n) ? a : -1;
    if (PASS == 1) smg.pL[tid] = (unsigned long long)(Xb + (size_t)(a >> 1) * DM);
  }
  __syncthreads();

  const char* Bsrc = (const char*)Wp +
      ((size_t)(e * ((PASS == 1) ? 32 : 8) + nTile) * ((PASS == 1) ? 16 : 64) +
       (size_t)kc * 32) * 16384;
  const char* Asrc = nullptr;
  unsigned long long sA0[4];
  if constexpr (PASS == 1) {
    const int sr = tid >> 3, sc = (tid & 7) * 16;
#pragma unroll
    for (int jj = 0; jj < 4; ++jj) {
      int row = jj * 32 + sr;
      sA0[jj] = smg.pL[row] + (unsigned)(sc ^ ((row & 7) << 4));  // source-swizzled gather
    }
  } else {
    Asrc = (const char*)Hp + ((size_t)t * 64 + kc * 32) * 16384;  // packed H, linear
  }

  const int wv = tid >> 6, lane = tid & 63;
  const int r0 = (wv >> 1) * 64, c0 = (wv & 1) * 64;

  f32x4 acc[4][4];
#pragma unroll
  for (int m = 0; m < 4; ++m)
#pragma unroll
    for (int nn = 0; nn < 4; ++nn) acc[m][nn] = (f32x4){0.f, 0.f, 0.f, 0.f};

  for (int kt = 0; kt < NK; ++kt) {
    if constexpr (PASS == 1) {
#pragma unroll
      for (int jj = 0; jj < 4; ++jj)
        gl_lds16(sA0[jj] + (unsigned)kt * 128, smg.As + jj * 4096 + tid * 16);
    } else {
#pragma unroll
      for (int jj = 0; jj < 4; ++jj)
        gl_lds16((unsigned long long)(Asrc + (size_t)kt * 16384 + jj * 4096 + tid * 16),
                 smg.As + jj * 4096 + tid * 16);
    }
#pragma unroll
    for (int jj = 0; jj < 4; ++jj)
      gl_lds16((unsigned long long)(Bsrc + (size_t)kt * 16384 + jj * 4096 + tid * 16),
               smg.Bs + jj * 4096 + tid * 16);
    WAITV0();
    BARRIER();
#pragma unroll
    for (int kk = 0; kk < 2; ++kk) {
      const int kb = kk * 64 + (lane >> 4) * 16;
      bf16x8 af[4], bfr[4];
#pragma unroll
      for (int m = 0; m < 4; ++m) {
        int row = r0 + m * 16 + (lane & 15);
        af[m] = *reinterpret_cast<const bf16x8*>(smg.As + row * 128 + (kb ^ ((row & 7) << 4)));
      }
#pragma unroll
      for (int nn = 0; nn < 4; ++nn) {
        int row = c0 + nn * 16 + (lane & 15);
        bfr[nn] = *reinterpret_cast<const bf16x8*>(smg.Bs + row * 128 + (kb ^ ((row & 7) << 4)));
      }
      __builtin_amdgcn_s_setprio(1);
#pragma unroll
      for (int m = 0; m < 4; ++m)
#pragma unroll
        for (int nn = 0; nn < 4; ++nn)
          acc[m][nn] = __builtin_amdgcn_mfma_f32_16x16x32_bf16(af[m], bfr[nn], acc[m][nn], 0, 0, 0);
      __builtin_amdgcn_s_setprio(0);
    }
    BARRIER();  // WAR before next stage overwrites
  }

  // epilogue — C/D layout: col = lane&15, row = (lane>>4)*4 + jr
#pragma unroll
  for (int m = 0; m < 4; ++m) {
#pragma unroll
    for (int jr = 0; jr < 4; ++jr) {
      int lr = r0 + m * 16 + (lane >> 4) * 4 + jr;
      if constexpr (PASS == 1) {
        // all rows written (padding rows dup last real; pass2 discards via aL<0)
#pragma unroll
        for (int nn = 0; nn < 4; ++nn) {
          int cg = nTile * 128 + c0 + nn * 16 + (lane & 15);
          float v = acc[m][nn][jr];
          size_t us = ((size_t)t * 64 + (cg >> 6)) * 8192 + (size_t)lr * 64 +
                      ((cg & 63) ^ ((lr & 7) << 3));
          Hp[us] = f2bf(v / (1.f + expf(-v)));  // swish, packed-swizzled H
        }
      } else {
        int a = smg.aL[lr];
        if (a < 0) continue;
        float w = wa[a];
        int tok = a >> 1;
        float* orow = out + (size_t)tok * DM + nTile * 128 + c0 + (lane & 15);
#pragma unroll
        for (int nn = 0; nn < 4; ++nn)
          atomicAdd(&orow[nn * 16], w * acc[m][nn][jr]);  // 2 experts x 2 kc, commutative
      }
    }
  }
}

// ---------------- kernels ----------------
// prep1: blocks 0..4095 pack W1; blocks 4096..4351 run the router (fused launch).
__global__ __launch_bounds__(256, 4) void prep1(const float* __restrict__ x,
                                                const float* __restrict__ rtr,
                                                const float* __restrict__ W1,
                                                int* cnt, int* list, float* wa,
                                                ushort* __restrict__ Xb,
                                                ushort* __restrict__ Wp1) {
  __shared__ SMem sm;
  if (blockIdx.x < 4096) {
    pack_block(W1, Wp1, blockIdx.x, DM, DFF, sm.t);
    return;
  }
  router_block(x, rtr, cnt, list, wa, Xb, blockIdx.x - 4096, sm.rl);
}

// pass1 (+ optional fused pack of W2 in blocks >= 4352 when workspace permits):
// pass1 is latency-bound (2.7 TB/s HBM) -> the ~200 MB pack stream hides in its
// idle memory slots instead of costing a serial ~55 us launch.
__global__ __launch_bounds__(256, 4) void moe_p1(const ushort* __restrict__ Xb,
                                                 const ushort* __restrict__ Wp1,
                                                 ushort* __restrict__ Hp,
                                                 const int* __restrict__ cnt,
                                                 const int* __restrict__ list,
                                                 const float* __restrict__ wa,
                                                 float* __restrict__ out,
                                                 const float* __restrict__ W2,
                                                 ushort* __restrict__ Wp2) {
  __shared__ SMem sm;
  if (blockIdx.x >= 4352) {
    pack_block(W2, Wp2, blockIdx.x - 4352, DFF, DM, sm.t);
    return;
  }
  gemm_body<1>(sm.g, blockIdx.x, Xb, Wp1, Hp, cnt, list, wa, out);
}

__global__ __launch_bounds__(256, 4) void moe_p2(const ushort* __restrict__ Wp2,
                                                 ushort* __restrict__ Hp,
                                                 const int* __restrict__ cnt,
                                                 const int* __restrict__ list,
                                                 const float* __restrict__ wa,
                                                 float* __restrict__ out) {
  __shared__ SMem sm;
  gemm_body<2>(sm.g, blockIdx.x, nullptr, Wp2, Hp, cnt, list, wa, out);
}

// fallback standalone W2 pack (serial, aliased workspace)
__global__ __launch_bounds__(256, 4) void pack_w2_k(const float* __restrict__ W2,
                                                    ushort* __restrict__ Wp2) {
  __shared__ SMem sm;
  pack_block(W2, Wp2, blockIdx.x, DFF, DM, sm.t);
}

extern "C" void kernel_launch(void* const* d_in, const int* in_sizes, int n_in,
                              void* d_out, int out_size, void* d_ws, size_t ws_size,
                              hipStream_t stream) {
  const float* x = (const float*)d_in[0];
  const float* router = (const float*)d_in[1];
  const float* W1 = (const float*)d_in[2];
  const float* W2 = (const float*)d_in[3];
  float* out = (float*)d_out;
  char* ws = (char*)d_ws;

  // layout: Xb 16 MiB | Wp1 64 MiB | Hp 136 MiB | misc | [Wp2 64 MiB if room]
  ushort* Xb  = (ushort*)(ws);
  ushort* Wp1 = (ushort*)(ws + (16ull << 20));
  ushort* Hp  = (ushort*)(ws + (80ull << 20));
  size_t oMisc = (80ull << 20) + (size_t)MAXT * 64 * 16384;
  int* cnt  = (int*)(ws + oMisc);
  int* list = (int*)(ws + oMisc + 1024);
  float* wa = (float*)(ws + oMisc + 1024 + (size_t)NE * NTOK * 4);
  size_t oEnd = oMisc + 1024 + (size_t)NE * NTOK * 4 + (size_t)NTOK * 2 * 4;
  size_t oWp2 = (oEnd + 255) & ~(size_t)255;
  const bool fused = ws_size >= oWp2 + (64ull << 20);  // ws_size fixed -> deterministic
  ushort* Wp2 = fused ? (ushort*)(ws + oWp2) : (ushort*)ws;  // fallback: alias Xb/Wp1 (dead after pass1)

  hipMemsetAsync(out, 0, (size_t)NTOK * DM * sizeof(float), stream);
  hipMemsetAsync(cnt, 0, NE * sizeof(int), stream);

  prep1<<<4096 + 256, 256, 0, stream>>>(x, router, W1, cnt, list, wa, Xb, Wp1);

  if (fused) {
    moe_p1<<<4352 + 4096, 256, 0, stream>>>(Xb, Wp1, Hp, cnt, list, wa, out, W2, Wp2);
  } else {
    moe_p1<<<4352, 256, 0, stream>>>(Xb, Wp1, Hp, cnt, list, wa, out, W2, Wp2);
    pack_w2_k<<<4096, 256, 0, stream>>>(W2, Wp2);
  }

  moe_p2<<<2176, 256, 0, stream>>>(Wp2, Hp, cnt, list, wa, out);
}